// Round 2
// baseline (4390.012 us; speedup 1.0000x reference)
//
#include <hip/hip_runtime.h>
#include <math.h>

// Problem constants (MambaBlock): B=2, L=4096, D=2048, H=32, DS=64, K=4
#define BB   2
#define LL   4096
#define DD   2048
#define HH   32
#define DSS  64
#define MM   (BB * LL)        // 8192 rows
#define N3   (3 * HH * DSS)   // 6144
#define NCH  64               // scan chunks
#define CLN  64               // steps per chunk (NCH*CLN == LL)
#define EPSF 1e-6f

typedef unsigned short bf16;  // raw bf16 bits — we own the representation

__device__ __forceinline__ float bf2f(bf16 u) {
    union { unsigned int i; float f; } v;
    v.i = ((unsigned int)u) << 16;
    return v.f;
}
__device__ __forceinline__ bf16 f2bf(float f) {
    union { float f; unsigned int u; } v;
    v.f = f;
    unsigned int r = (v.u >> 16) & 1u;       // round to nearest even
    return (bf16)((v.u + 0x7fffu + r) >> 16);
}
__device__ __forceinline__ float sigmoidf_(float v) {
    return 1.0f / (1.0f + expf(-v));
}

// ---------------------------------------------------------------- RMSNorm ---
// One block per row. 256 threads, 8 floats each; bf16 output.
__global__ __launch_bounds__(256) void rms_kernel(const float* __restrict__ x,
                                                  const float* __restrict__ w,
                                                  bf16* __restrict__ xn) {
    int row = blockIdx.x;
    const float4* x4 = (const float4*)(x + (size_t)row * DD);
    ushort4* o4 = (ushort4*)(xn + (size_t)row * DD);
    const float4* w4 = (const float4*)w;
    int t = threadIdx.x;
    float4 v0 = x4[t], v1 = x4[t + 256];
    float ss = v0.x * v0.x + v0.y * v0.y + v0.z * v0.z + v0.w * v0.w +
               v1.x * v1.x + v1.y * v1.y + v1.z * v1.z + v1.w * v1.w;
#pragma unroll
    for (int off = 32; off >= 1; off >>= 1) ss += __shfl_down(ss, off, 64);
    __shared__ float red[4];
    if ((t & 63) == 0) red[t >> 6] = ss;
    __syncthreads();
    float tot = red[0] + red[1] + red[2] + red[3];
    float inv = 1.0f / sqrtf(tot * (1.0f / DD) + EPSF);
    float4 wa = w4[t], wb = w4[t + 256];
    ushort4 r0, r1;
    r0.x = f2bf(v0.x * inv * wa.x); r0.y = f2bf(v0.y * inv * wa.y);
    r0.z = f2bf(v0.z * inv * wa.z); r0.w = f2bf(v0.w * inv * wa.w);
    r1.x = f2bf(v1.x * inv * wb.x); r1.y = f2bf(v1.y * inv * wb.y);
    r1.z = f2bf(v1.z * inv * wb.z); r1.w = f2bf(v1.w * inv * wb.w);
    o4[t] = r0; o4[t + 256] = r1;
}

// ----------------------------------------------------- causal conv + SiLU ---
// xc[b,l,d] = silu(conv_b[d] + sum_k xn[b, l-3+k, d] * conv_w[d,k])
__global__ __launch_bounds__(256) void conv_silu_kernel(const bf16* __restrict__ xn,
                                                        const float* __restrict__ cw,
                                                        const float* __restrict__ cb,
                                                        bf16* __restrict__ xc) {
    int l = blockIdx.x;
    int b = blockIdx.y;
    size_t base = ((size_t)b * LL + l) * DD;
#pragma unroll
    for (int i = 0; i < 8; ++i) {
        int d = (i << 8) + threadIdx.x;
        float4 w = ((const float4*)cw)[d];  // conv_w[d, 0..3]
        float acc = cb[d];
        if (l >= 3) {
            acc += bf2f(xn[base - 3 * (size_t)DD + d]) * w.x +
                   bf2f(xn[base - 2 * (size_t)DD + d]) * w.y +
                   bf2f(xn[base - 1 * (size_t)DD + d]) * w.z +
                   bf2f(xn[base + d]) * w.w;
        } else {
            const float wv[4] = {w.x, w.y, w.z, w.w};
#pragma unroll
            for (int k = 0; k < 4; ++k) {
                int ls = l - 3 + k;
                if (ls >= 0) acc += bf2f(xn[((size_t)b * LL + ls) * DD + d]) * wv[k];
            }
        }
        xc[base + d] = f2bf(acc * sigmoidf_(acc));
    }
}

// ----------------------------------------------- GEMM: bf16 A, fp32 weights --
// out[M,N] = A[M,K] @ Bw[K,N] + bias[N]  (+ epilogue)
// EPI: 0 = none, 1 = sigmoid, 2 = + add[M,N] (residual)
// OutT: float or bf16. 64x64 tile, BK=16, 256 threads, 4x4 accum/thread.
template <int EPI, typename OutT>
__global__ __launch_bounds__(256) void gemm_bf(const bf16* __restrict__ A,
                                               const float* __restrict__ Bw,
                                               const float* __restrict__ bias,
                                               const float* __restrict__ add,
                                               OutT* __restrict__ out,
                                               int Ndim, int Kdim) {
    __shared__ float As[16][64];
    __shared__ float Bs[16][64];
    const int tid = threadIdx.x;
    const int tx = tid & 15, ty = tid >> 4;
    const int n0 = blockIdx.x << 6, m0 = blockIdx.y << 6;
    const int a_row = tid >> 2;          // 0..63
    const int a_col = (tid & 3) << 2;    // 0,4,8,12
    const int b_row = tid >> 4;          // 0..15
    const int b_col = (tid & 15) << 2;   // 0..60
    const bf16* Ap = A + (size_t)(m0 + a_row) * Kdim + a_col;
    const float* Bp = Bw + (size_t)b_row * Ndim + n0 + b_col;
    float acc[4][4] = {};
    for (int k0 = 0; k0 < Kdim; k0 += 16) {
        ushort4 av = *(const ushort4*)(Ap + k0);
        float4 bv = *(const float4*)(Bp + (size_t)k0 * Ndim);
        __syncthreads();
        As[a_col + 0][a_row] = bf2f(av.x);
        As[a_col + 1][a_row] = bf2f(av.y);
        As[a_col + 2][a_row] = bf2f(av.z);
        As[a_col + 3][a_row] = bf2f(av.w);
        *(float4*)&Bs[b_row][b_col] = bv;
        __syncthreads();
#pragma unroll
        for (int kk = 0; kk < 16; ++kk) {
            float4 a4 = *(const float4*)&As[kk][ty << 2];
            float4 b4 = *(const float4*)&Bs[kk][tx << 2];
            float ar[4] = {a4.x, a4.y, a4.z, a4.w};
            float br[4] = {b4.x, b4.y, b4.z, b4.w};
#pragma unroll
            for (int i = 0; i < 4; ++i)
#pragma unroll
                for (int j = 0; j < 4; ++j) acc[i][j] += ar[i] * br[j];
        }
    }
    const int n = n0 + (tx << 2);
    float4 bi4 = *(const float4*)(bias + n);
    const float bb[4] = {bi4.x, bi4.y, bi4.z, bi4.w};
#pragma unroll
    for (int i = 0; i < 4; ++i) {
        int m = m0 + (ty << 2) + i;
        size_t o = (size_t)m * Ndim + n;
        float r[4];
#pragma unroll
        for (int j = 0; j < 4; ++j) {
            float v = acc[i][j] + bb[j];
            if (EPI == 1) v = sigmoidf_(v);
            r[j] = v;
        }
        if (EPI == 2) {
            float4 ad = *(const float4*)(add + o);
            r[0] += ad.x; r[1] += ad.y; r[2] += ad.z; r[3] += ad.w;
        }
        if constexpr (sizeof(OutT) == 4) {
            float4 st = {r[0], r[1], r[2], r[3]};
            *(float4*)((float*)out + o) = st;
        } else {
            ushort4 st = {f2bf(r[0]), f2bf(r[1]), f2bf(r[2]), f2bf(r[3])};
            *(ushort4*)((bf16*)out + o) = st;
        }
    }
}

// ------------------------------------------------------------- SSM scan -----
// p[b,l,h,j,s] (bf16) at flat ((b*L+l)*6144 + h*192 + j*64 + s);
// j=0 delta(pre-sigmoid), j=1 B, j=2 C.  h = sigmoid(delta)*h + B; ssm = C*h.

// phase 1: per-chunk affine composition h_out = a*h_in + b
__global__ __launch_bounds__(64) void scan_phase1(const bf16* __restrict__ p,
                                                  float* __restrict__ cA,
                                                  float* __restrict__ cB) {
    int c = blockIdx.x, h = blockIdx.y, b = blockIdx.z, s = threadIdx.x;
    size_t base = ((size_t)(b * LL + c * CLN)) * N3 + h * (3 * DSS) + s;
    float a = 1.0f, bb = 0.0f;
    for (int i = 0; i < CLN; ++i) {
        float d = sigmoidf_(bf2f(p[base]));
        float Bv = bf2f(p[base + DSS]);
        a *= d;
        bb = d * bb + Bv;
        base += N3;
    }
    int idx = ((b * HH + h) * NCH + c) * DSS + s;
    cA[idx] = a;
    cB[idx] = bb;
}

// phase 2: serial prefix over chunks; h at chunk starts + h_last
__global__ __launch_bounds__(64) void scan_phase2(const float* __restrict__ state,
                                                  const float* __restrict__ cA,
                                                  const float* __restrict__ cB,
                                                  float* __restrict__ cH,
                                                  float* __restrict__ hlast) {
    int h = blockIdx.x, b = blockIdx.y, s = threadIdx.x;
    float hp = state[(b * HH + h) * DSS + s];
    int base = ((b * HH + h) * NCH) * DSS + s;
    for (int c = 0; c < NCH; ++c) {
        cH[base + c * DSS] = hp;
        hp = cA[base + c * DSS] * hp + cB[base + c * DSS];
    }
    hlast[(b * HH + h) * DSS + s] = hp;
}

// phase 3: replay within chunk; fused mixed = gate*C*h + (1-gate)*xn
__global__ __launch_bounds__(64) void scan_phase3(const bf16* __restrict__ p,
                                                  const float* __restrict__ cH,
                                                  const float* __restrict__ gate,
                                                  const bf16* __restrict__ xn,
                                                  bf16* __restrict__ mixed) {
    int c = blockIdx.x, h = blockIdx.y, b = blockIdx.z, s = threadIdx.x;
    float hp = cH[((b * HH + h) * NCH + c) * DSS + s];
    size_t prow = ((size_t)(b * LL + c * CLN)) * N3 + h * (3 * DSS) + s;
    size_t grow = ((size_t)(b * LL + c * CLN)) * DD + h * DSS + s;
    for (int i = 0; i < CLN; ++i) {
        float d = sigmoidf_(bf2f(p[prow]));
        float Bv = bf2f(p[prow + DSS]);
        float Cv = bf2f(p[prow + 2 * DSS]);
        hp = d * hp + Bv;
        float ssm = Cv * hp;
        float g = gate[grow];
        float xv = bf2f(xn[grow]);
        mixed[grow] = f2bf(g * ssm + (1.0f - g) * xv);
        prow += N3;
        grow += DD;
    }
}

// ---------------------------------------------------------------------------
extern "C" void kernel_launch(void* const* d_in, const int* in_sizes, int n_in,
                              void* d_out, int out_size, void* d_ws, size_t ws_size,
                              hipStream_t stream) {
    const float* x      = (const float*)d_in[0];
    const float* state  = (const float*)d_in[1];
    const float* norm_w = (const float*)d_in[2];
    const float* conv_w = (const float*)d_in[3];
    const float* conv_b = (const float*)d_in[4];
    const float* pp_w   = (const float*)d_in[5];
    const float* pp_b   = (const float*)d_in[6];
    const float* gp_w   = (const float*)d_in[7];
    const float* gp_b   = (const float*)d_in[8];
    const float* op_w   = (const float*)d_in[9];
    const float* op_b   = (const float*)d_in[10];

    float* y     = (float*)d_out;                 // M*D floats
    float* hlast = y + (size_t)MM * DD;           // B*H*DS floats

    // workspace layout (bf16 big buffers, fp32 small):
    //   xn (MM*DD bf16, 32MB) | xc/mixed (MM*DD bf16, 32MB) |
    //   p (MM*N3 bf16, 96MB)  | cA | cB | cH (each 1MB fp32)   total ~172MB
    char* ws = (char*)d_ws;
    bf16* xn    = (bf16*)ws;
    bf16* xc    = xn + (size_t)MM * DD;           // also "mixed" after phase3
    bf16* p     = xc + (size_t)MM * DD;
    float* cA   = (float*)(p + (size_t)MM * N3);
    float* cB   = cA + (size_t)BB * HH * NCH * DSS;
    float* cH   = cB + (size_t)BB * HH * NCH * DSS;
    // gate (fp32) lives in d_out's y region until the final GEMM overwrites it
    float* gate  = y;
    bf16* mixed = xc;

    // 1. RMSNorm (fp32 in → bf16 out)
    rms_kernel<<<MM, 256, 0, stream>>>(x, norm_w, xn);
    // 2. causal conv + SiLU
    conv_silu_kernel<<<dim3(LL, BB), 256, 0, stream>>>(xn, conv_w, conv_b, xc);
    // 3. gate = sigmoid(xc @ gp_w + gp_b)   [M x 2048] fp32 out (in d_out)
    gemm_bf<1, float><<<dim3(DD / 64, MM / 64), 256, 0, stream>>>(
        xc, gp_w, gp_b, nullptr, gate, DD, DD);
    // 4. p = xn @ pp_w + pp_b               [M x 6144] bf16 out
    gemm_bf<0, bf16><<<dim3(N3 / 64, MM / 64), 256, 0, stream>>>(
        xn, pp_w, pp_b, nullptr, p, N3, DD);
    // 5-7. chunked SSM scan fused with mixing
    scan_phase1<<<dim3(NCH, HH, BB), 64, 0, stream>>>(p, cA, cB);
    scan_phase2<<<dim3(HH, BB), 64, 0, stream>>>(state, cA, cB, cH, hlast);
    scan_phase3<<<dim3(NCH, HH, BB), 64, 0, stream>>>(p, cH, gate, xn, mixed);
    // 8. y = mixed @ op_w + op_b + x        [M x 2048] fp32 out
    gemm_bf<2, float><<<dim3(DD / 64, MM / 64), 256, 0, stream>>>(
        mixed, op_w, op_b, x, y, DD, DD);
}

// Round 3
// 817.899 us; speedup vs baseline: 5.3674x; 5.3674x over previous
//
#include <hip/hip_runtime.h>
#include <math.h>

// Problem constants (MambaBlock): B=2, L=4096, D=2048, H=32, DS=64, K=4
#define BB   2
#define LL   4096
#define DD   2048
#define HH   32
#define DSS  64
#define MM   (BB * LL)        // 8192 rows
#define N3   (3 * HH * DSS)   // 6144
#define NCH  64               // scan chunks
#define CLN  64               // steps per chunk (NCH*CLN == LL)
#define EPSF 1e-6f

typedef unsigned short bf16;  // raw bf16 bits — we own the representation
typedef __attribute__((ext_vector_type(8))) short bf16x8;  // MFMA A/B frag (4 VGPRs)
typedef __attribute__((ext_vector_type(4))) float f32x4;   // MFMA C/D frag

__device__ __forceinline__ float bf2f(bf16 u) {
    union { unsigned int i; float f; } v;
    v.i = ((unsigned int)u) << 16;
    return v.f;
}
__device__ __forceinline__ bf16 f2bf(float f) {
    union { float f; unsigned int u; } v;
    v.f = f;
    unsigned int r = (v.u >> 16) & 1u;       // round to nearest even
    return (bf16)((v.u + 0x7fffu + r) >> 16);
}
__device__ __forceinline__ float sigmoidf_(float v) {
    return 1.0f / (1.0f + expf(-v));
}
__device__ __forceinline__ void gload16(const void* g, void* l) {
    __builtin_amdgcn_global_load_lds(
        (const __attribute__((address_space(1))) void*)g,
        (__attribute__((address_space(3))) void*)l, 16, 0, 0);
}

// ---------------------------------------------------------------- RMSNorm ---
__global__ __launch_bounds__(256) void rms_kernel(const float* __restrict__ x,
                                                  const float* __restrict__ w,
                                                  bf16* __restrict__ xn) {
    int row = blockIdx.x;
    const float4* x4 = (const float4*)(x + (size_t)row * DD);
    ushort4* o4 = (ushort4*)(xn + (size_t)row * DD);
    const float4* w4 = (const float4*)w;
    int t = threadIdx.x;
    float4 v0 = x4[t], v1 = x4[t + 256];
    float ss = v0.x * v0.x + v0.y * v0.y + v0.z * v0.z + v0.w * v0.w +
               v1.x * v1.x + v1.y * v1.y + v1.z * v1.z + v1.w * v1.w;
#pragma unroll
    for (int off = 32; off >= 1; off >>= 1) ss += __shfl_down(ss, off, 64);
    __shared__ float red[4];
    if ((t & 63) == 0) red[t >> 6] = ss;
    __syncthreads();
    float tot = red[0] + red[1] + red[2] + red[3];
    float inv = 1.0f / sqrtf(tot * (1.0f / DD) + EPSF);
    float4 wa = w4[t], wb = w4[t + 256];
    ushort4 r0, r1;
    r0.x = f2bf(v0.x * inv * wa.x); r0.y = f2bf(v0.y * inv * wa.y);
    r0.z = f2bf(v0.z * inv * wa.z); r0.w = f2bf(v0.w * inv * wa.w);
    r1.x = f2bf(v1.x * inv * wb.x); r1.y = f2bf(v1.y * inv * wb.y);
    r1.z = f2bf(v1.z * inv * wb.z); r1.w = f2bf(v1.w * inv * wb.w);
    o4[t] = r0; o4[t + 256] = r1;
}

// ----------------------------------------------------- causal conv + SiLU ---
__global__ __launch_bounds__(256) void conv_silu_kernel(const bf16* __restrict__ xn,
                                                        const float* __restrict__ cw,
                                                        const float* __restrict__ cb,
                                                        bf16* __restrict__ xc) {
    int l = blockIdx.x;
    int b = blockIdx.y;
    size_t base = ((size_t)b * LL + l) * DD;
#pragma unroll
    for (int i = 0; i < 8; ++i) {
        int d = (i << 8) + threadIdx.x;
        float4 w = ((const float4*)cw)[d];
        float acc = cb[d];
        if (l >= 3) {
            acc += bf2f(xn[base - 3 * (size_t)DD + d]) * w.x +
                   bf2f(xn[base - 2 * (size_t)DD + d]) * w.y +
                   bf2f(xn[base - 1 * (size_t)DD + d]) * w.z +
                   bf2f(xn[base + d]) * w.w;
        } else {
            const float wv[4] = {w.x, w.y, w.z, w.w};
#pragma unroll
            for (int k = 0; k < 4; ++k) {
                int ls = l - 3 + k;
                if (ls >= 0) acc += bf2f(xn[((size_t)b * LL + ls) * DD + d]) * wv[k];
            }
        }
        xc[base + d] = f2bf(acc * sigmoidf_(acc));
    }
}

// ------------------------------------- weight transpose+convert: fp32->bf16 --
// W[Kdim][Ndim] fp32 -> WT[Ndim][Kdim] bf16, 32x32 LDS tiles.
__global__ __launch_bounds__(256) void transpose_bf(const float* __restrict__ W,
                                                    bf16* __restrict__ WT,
                                                    int Kdim, int Ndim) {
    __shared__ float t[32][33];
    int n0 = blockIdx.x << 5, k0 = blockIdx.y << 5;
    int tx = threadIdx.x & 31;
    int ty = threadIdx.x >> 5;   // 0..7
#pragma unroll
    for (int i = 0; i < 32; i += 8)
        t[ty + i][tx] = W[(size_t)(k0 + ty + i) * Ndim + n0 + tx];
    __syncthreads();
#pragma unroll
    for (int i = 0; i < 32; i += 8)
        WT[(size_t)(n0 + ty + i) * Kdim + k0 + tx] = f2bf(t[tx][ty + i]);
}

// -------------------------------------------------- MFMA bf16 GEMM (m97) ----
// out[M,N] = A[M,K] @ W[K,N] + bias  with W given TRANSPOSED as Bt[N][K] bf16.
// EPI: 0 none, 1 sigmoid, 2 +add (residual). OutT: float or bf16.
// 128x128 tile, BK=32, 256 threads (4 waves), 4x4 16x16x32 MFMA per wave.
template <int EPI, typename OutT>
__global__ __launch_bounds__(256) void gemm_mfma(const bf16* __restrict__ A,
                                                 const bf16* __restrict__ Bt,
                                                 const float* __restrict__ bias,
                                                 const float* __restrict__ add,
                                                 OutT* __restrict__ out,
                                                 int Ndim, int Kdim) {
    __shared__ __align__(16) bf16 As[128 * 32];
    __shared__ __align__(16) bf16 Bs[128 * 32];
    const int tid  = threadIdx.x;
    const int wave = tid >> 6;
    const int lane = tid & 63;
    const int m0 = blockIdx.y << 7;
    const int n0 = blockIdx.x << 7;

    // staging: chunk = wave*2+pass covers 16 rows (1 KB); lane i -> row c*16+(i>>2),
    // element col (i&3)*8. LDS elem offset = chunk*512 + lane*8 (wave-uniform base + lane*16B).
    const int srow = lane >> 2;          // 0..15
    const int scol = (lane & 3) << 3;    // 0,8,16,24
    const bf16* gA0 = A  + (size_t)(m0 + wave * 32 + srow) * Kdim + scol;
    const bf16* gA1 = gA0 + (size_t)16 * Kdim;
    const bf16* gB0 = Bt + (size_t)(n0 + wave * 32 + srow) * Kdim + scol;
    const bf16* gB1 = gB0 + (size_t)16 * Kdim;
    bf16* lA0 = As + (wave * 2    ) * 512 + lane * 8;
    bf16* lA1 = As + (wave * 2 + 1) * 512 + lane * 8;
    bf16* lB0 = Bs + (wave * 2    ) * 512 + lane * 8;
    bf16* lB1 = Bs + (wave * 2 + 1) * 512 + lane * 8;

    const int wm = (wave >> 1) << 6;     // 0 / 64
    const int wn = (wave & 1) << 6;      // 0 / 64
    const int fr = lane & 15;            // m (A) / n (B) within 16-tile
    const int kg = lane >> 4;            // k-group 0..3

    f32x4 acc[4][4] = {};
    for (int k0 = 0; k0 < Kdim; k0 += 32) {
        __syncthreads();
        gload16(gA0 + k0, lA0);
        gload16(gA1 + k0, lA1);
        gload16(gB0 + k0, lB0);
        gload16(gB1 + k0, lB1);
        __syncthreads();
        bf16x8 af[4], bf_[4];
#pragma unroll
        for (int i = 0; i < 4; ++i) {
            af[i]  = *(const bf16x8*)&As[(wm + i * 16 + fr) * 32 + kg * 8];
            bf_[i] = *(const bf16x8*)&Bs[(wn + i * 16 + fr) * 32 + kg * 8];
        }
#pragma unroll
        for (int i = 0; i < 4; ++i)
#pragma unroll
            for (int j = 0; j < 4; ++j)
                acc[i][j] = __builtin_amdgcn_mfma_f32_16x16x32_bf16(
                    af[i], bf_[j], acc[i][j], 0, 0, 0);
    }

    // epilogue: C/D layout col(n)=lane&15, row(m)=kg*4+reg  [m89/m91 verified]
    const int baseRow = m0 + wm + kg * 4;
    const int baseCol = n0 + wn + fr;
#pragma unroll
    for (int i = 0; i < 4; ++i) {
#pragma unroll
        for (int r = 0; r < 4; ++r) {
            int m = baseRow + i * 16 + r;
            size_t rowoff = (size_t)m * Ndim + baseCol;
#pragma unroll
            for (int j = 0; j < 4; ++j) {
                float v = acc[i][j][r] + bias[baseCol + j * 16];
                if (EPI == 1) v = sigmoidf_(v);
                if (EPI == 2) v += add[rowoff + j * 16];
                if constexpr (sizeof(OutT) == 4)
                    ((float*)out)[rowoff + j * 16] = v;
                else
                    ((bf16*)out)[rowoff + j * 16] = f2bf(v);
            }
        }
    }
}

// ------------------------------------------------------------- SSM scan -----
__global__ __launch_bounds__(64) void scan_phase1(const bf16* __restrict__ p,
                                                  float* __restrict__ cA,
                                                  float* __restrict__ cB) {
    int c = blockIdx.x, h = blockIdx.y, b = blockIdx.z, s = threadIdx.x;
    size_t base = ((size_t)(b * LL + c * CLN)) * N3 + h * (3 * DSS) + s;
    float a = 1.0f, bb = 0.0f;
    for (int i = 0; i < CLN; ++i) {
        float d = sigmoidf_(bf2f(p[base]));
        float Bv = bf2f(p[base + DSS]);
        a *= d;
        bb = d * bb + Bv;
        base += N3;
    }
    int idx = ((b * HH + h) * NCH + c) * DSS + s;
    cA[idx] = a;
    cB[idx] = bb;
}

__global__ __launch_bounds__(64) void scan_phase2(const float* __restrict__ state,
                                                  const float* __restrict__ cA,
                                                  const float* __restrict__ cB,
                                                  float* __restrict__ cH,
                                                  float* __restrict__ hlast) {
    int h = blockIdx.x, b = blockIdx.y, s = threadIdx.x;
    float hp = state[(b * HH + h) * DSS + s];
    int base = ((b * HH + h) * NCH) * DSS + s;
    for (int c = 0; c < NCH; ++c) {
        cH[base + c * DSS] = hp;
        hp = cA[base + c * DSS] * hp + cB[base + c * DSS];
    }
    hlast[(b * HH + h) * DSS + s] = hp;
}

__global__ __launch_bounds__(64) void scan_phase3(const bf16* __restrict__ p,
                                                  const float* __restrict__ cH,
                                                  const float* __restrict__ gate,
                                                  const bf16* __restrict__ xn,
                                                  bf16* __restrict__ mixed) {
    int c = blockIdx.x, h = blockIdx.y, b = blockIdx.z, s = threadIdx.x;
    float hp = cH[((b * HH + h) * NCH + c) * DSS + s];
    size_t prow = ((size_t)(b * LL + c * CLN)) * N3 + h * (3 * DSS) + s;
    size_t grow = ((size_t)(b * LL + c * CLN)) * DD + h * DSS + s;
    for (int i = 0; i < CLN; ++i) {
        float d = sigmoidf_(bf2f(p[prow]));
        float Bv = bf2f(p[prow + DSS]);
        float Cv = bf2f(p[prow + 2 * DSS]);
        hp = d * hp + Bv;
        float ssm = Cv * hp;
        float g = gate[grow];
        float xv = bf2f(xn[grow]);
        mixed[grow] = f2bf(g * ssm + (1.0f - g) * xv);
        prow += N3;
        grow += DD;
    }
}

// ---------------------------------------------------------------------------
extern "C" void kernel_launch(void* const* d_in, const int* in_sizes, int n_in,
                              void* d_out, int out_size, void* d_ws, size_t ws_size,
                              hipStream_t stream) {
    const float* x      = (const float*)d_in[0];
    const float* state  = (const float*)d_in[1];
    const float* norm_w = (const float*)d_in[2];
    const float* conv_w = (const float*)d_in[3];
    const float* conv_b = (const float*)d_in[4];
    const float* pp_w   = (const float*)d_in[5];
    const float* pp_b   = (const float*)d_in[6];
    const float* gp_w   = (const float*)d_in[7];
    const float* gp_b   = (const float*)d_in[8];
    const float* op_w   = (const float*)d_in[9];
    const float* op_b   = (const float*)d_in[10];

    float* y     = (float*)d_out;                 // M*D floats
    float* hlast = y + (size_t)MM * DD;           // B*H*DS floats

    // ws: xn 32MB | xcbuf 32MB (xc -> pp_wT -> mixed) | p 96MB |
    //     cA,cB,cH 3MB | gp_wT 8MB | op_wT 8MB      total ~179MB
    const size_t BHND = (size_t)BB * HH * NCH * DSS;
    char* ws = (char*)d_ws;
    bf16* xn    = (bf16*)ws;
    bf16* xcbuf = xn + (size_t)MM * DD;
    bf16* p     = xcbuf + (size_t)MM * DD;
    float* cA   = (float*)(p + (size_t)MM * N3);
    float* cB   = cA + BHND;
    float* cH   = cB + BHND;
    bf16* gp_wT = (bf16*)(cH + BHND);
    bf16* op_wT = gp_wT + (size_t)DD * DD;
    bf16* pp_wT = xcbuf;   // 25MB fits in the 32MB xc buffer (xc dead after gate GEMM)
    float* gate = y;       // fp32 gate parked in d_out until final GEMM overwrites
    bf16* mixed = xcbuf;

    // 1. RMSNorm (fp32 -> bf16)
    rms_kernel<<<MM, 256, 0, stream>>>(x, norm_w, xn);
    // 2. causal conv + SiLU (bf16 -> bf16)
    conv_silu_kernel<<<dim3(LL, BB), 256, 0, stream>>>(xn, conv_w, conv_b, xcbuf);
    // 3a. gp_w -> bf16 transposed
    transpose_bf<<<dim3(DD / 32, DD / 32), 256, 0, stream>>>(gp_w, gp_wT, DD, DD);
    // 3b. gate = sigmoid(xc @ gp_w + gp_b)
    gemm_mfma<1, float><<<dim3(DD / 128, MM / 128), 256, 0, stream>>>(
        xcbuf, gp_wT, gp_b, nullptr, gate, DD, DD);
    // 4a. pp_w -> bf16 transposed (into xc buffer — xc is dead now)
    transpose_bf<<<dim3(N3 / 32, DD / 32), 256, 0, stream>>>(pp_w, pp_wT, DD, N3);
    // 4b. p = xn @ pp_w + pp_b  (bf16 out)
    gemm_mfma<0, bf16><<<dim3(N3 / 128, MM / 128), 256, 0, stream>>>(
        xn, pp_wT, pp_b, nullptr, p, N3, DD);
    // 5-7. chunked SSM scan fused with mixing (mixed overwrites pp_wT region)
    scan_phase1<<<dim3(NCH, HH, BB), 64, 0, stream>>>(p, cA, cB);
    scan_phase2<<<dim3(HH, BB), 64, 0, stream>>>(state, cA, cB, cH, hlast);
    scan_phase3<<<dim3(NCH, HH, BB), 64, 0, stream>>>(p, cH, gate, xn, mixed);
    // 8a. op_w -> bf16 transposed
    transpose_bf<<<dim3(DD / 32, DD / 32), 256, 0, stream>>>(op_w, op_wT, DD, DD);
    // 8b. y = mixed @ op_w + op_b + x
    gemm_mfma<2, float><<<dim3(DD / 128, MM / 128), 256, 0, stream>>>(
        mixed, op_wT, op_b, x, y, DD, DD);
}

// Round 4
// 701.244 us; speedup vs baseline: 6.2603x; 1.1664x over previous
//
#include <hip/hip_runtime.h>
#include <math.h>

// Problem constants (MambaBlock): B=2, L=4096, D=2048, H=32, DS=64, K=4
#define BB   2
#define LL   4096
#define DD   2048
#define HH   32
#define DSS  64
#define MM   (BB * LL)        // 8192 rows
#define N3   (3 * HH * DSS)   // 6144
#define NCH  64               // scan chunks
#define CLN  64               // steps per chunk (NCH*CLN == LL)
#define EPSF 1e-6f

typedef unsigned short bf16;  // raw bf16 bits — we own the representation
typedef __attribute__((ext_vector_type(8))) short bf16x8;  // MFMA A/B frag (4 VGPRs)
typedef __attribute__((ext_vector_type(4))) float f32x4;   // MFMA C/D frag

__device__ __forceinline__ float bf2f(bf16 u) {
    union { unsigned int i; float f; } v;
    v.i = ((unsigned int)u) << 16;
    return v.f;
}
__device__ __forceinline__ bf16 f2bf(float f) {
    union { float f; unsigned int u; } v;
    v.f = f;
    unsigned int r = (v.u >> 16) & 1u;       // round to nearest even
    return (bf16)((v.u + 0x7fffu + r) >> 16);
}
__device__ __forceinline__ float sigmoidf_(float v) {
    return 1.0f / (1.0f + __expf(-v));
}
__device__ __forceinline__ void gload16(const void* g, void* l) {
    __builtin_amdgcn_global_load_lds(
        (const __attribute__((address_space(1))) void*)g,
        (__attribute__((address_space(3))) void*)l, 16, 0, 0);
}

// ---------------------------------------------------------------- RMSNorm ---
__global__ __launch_bounds__(256) void rms_kernel(const float* __restrict__ x,
                                                  const float* __restrict__ w,
                                                  bf16* __restrict__ xn) {
    int row = blockIdx.x;
    const float4* x4 = (const float4*)(x + (size_t)row * DD);
    ushort4* o4 = (ushort4*)(xn + (size_t)row * DD);
    const float4* w4 = (const float4*)w;
    int t = threadIdx.x;
    float4 v0 = x4[t], v1 = x4[t + 256];
    float ss = v0.x * v0.x + v0.y * v0.y + v0.z * v0.z + v0.w * v0.w +
               v1.x * v1.x + v1.y * v1.y + v1.z * v1.z + v1.w * v1.w;
#pragma unroll
    for (int off = 32; off >= 1; off >>= 1) ss += __shfl_down(ss, off, 64);
    __shared__ float red[4];
    if ((t & 63) == 0) red[t >> 6] = ss;
    __syncthreads();
    float tot = red[0] + red[1] + red[2] + red[3];
    float inv = 1.0f / sqrtf(tot * (1.0f / DD) + EPSF);
    float4 wa = w4[t], wb = w4[t + 256];
    ushort4 r0, r1;
    r0.x = f2bf(v0.x * inv * wa.x); r0.y = f2bf(v0.y * inv * wa.y);
    r0.z = f2bf(v0.z * inv * wa.z); r0.w = f2bf(v0.w * inv * wa.w);
    r1.x = f2bf(v1.x * inv * wb.x); r1.y = f2bf(v1.y * inv * wb.y);
    r1.z = f2bf(v1.z * inv * wb.z); r1.w = f2bf(v1.w * inv * wb.w);
    o4[t] = r0; o4[t + 256] = r1;
}

// ----------------------------------------------------- causal conv + SiLU ---
__global__ __launch_bounds__(256) void conv_silu_kernel(const bf16* __restrict__ xn,
                                                        const float* __restrict__ cw,
                                                        const float* __restrict__ cb,
                                                        bf16* __restrict__ xc) {
    int l = blockIdx.x;
    int b = blockIdx.y;
    size_t base = ((size_t)b * LL + l) * DD;
#pragma unroll
    for (int i = 0; i < 8; ++i) {
        int d = (i << 8) + threadIdx.x;
        float4 w = ((const float4*)cw)[d];
        float acc = cb[d];
        if (l >= 3) {
            acc += bf2f(xn[base - 3 * (size_t)DD + d]) * w.x +
                   bf2f(xn[base - 2 * (size_t)DD + d]) * w.y +
                   bf2f(xn[base - 1 * (size_t)DD + d]) * w.z +
                   bf2f(xn[base + d]) * w.w;
        } else {
            const float wv[4] = {w.x, w.y, w.z, w.w};
#pragma unroll
            for (int k = 0; k < 4; ++k) {
                int ls = l - 3 + k;
                if (ls >= 0) acc += bf2f(xn[((size_t)b * LL + ls) * DD + d]) * wv[k];
            }
        }
        xc[base + d] = f2bf(acc * sigmoidf_(acc));
    }
}

// ------------------------------------- weight transpose+convert: fp32->bf16 --
__global__ __launch_bounds__(256) void transpose_bf(const float* __restrict__ W,
                                                    bf16* __restrict__ WT,
                                                    int Kdim, int Ndim) {
    __shared__ float t[32][33];
    int n0 = blockIdx.x << 5, k0 = blockIdx.y << 5;
    int tx = threadIdx.x & 31;
    int ty = threadIdx.x >> 5;   // 0..7
#pragma unroll
    for (int i = 0; i < 32; i += 8)
        t[ty + i][tx] = W[(size_t)(k0 + ty + i) * Ndim + n0 + tx];
    __syncthreads();
#pragma unroll
    for (int i = 0; i < 32; i += 8)
        WT[(size_t)(n0 + ty + i) * Kdim + k0 + tx] = f2bf(t[tx][ty + i]);
}

// ------------------------------------------- MFMA bf16 GEMM (BK=64, swizzled)
// out[M,N] = A[M,K] @ W[K,N] + bias  with W given TRANSPOSED as Bt[N][K] bf16.
// EPI: 0 none, 1 sigmoid, 2 +add (residual). OutT: float or bf16.
// 128x128 tile, BK=64, 256 threads (4 waves), 4x4 16x16x32 MFMA per wave x2 K-phases.
// LDS layout: [row][colgrp^(row&7)] with 8-elem (16B) col groups -> 2-way banks.
template <int EPI, typename OutT>
__global__ __launch_bounds__(256) void gemm_mfma(const bf16* __restrict__ A,
                                                 const bf16* __restrict__ Bt,
                                                 const float* __restrict__ bias,
                                                 const float* __restrict__ add,
                                                 OutT* __restrict__ out,
                                                 int Ndim, int Kdim) {
    __shared__ __align__(16) bf16 As[128 * 64];   // 16 KB
    __shared__ __align__(16) bf16 Bs[128 * 64];   // 16 KB
    const int tid  = threadIdx.x;
    const int wave = tid >> 6;
    const int lane = tid & 63;
    const int m0 = blockIdx.y << 7;
    const int n0 = blockIdx.x << 7;

    // staging: chunk = wave*4+p covers 8 rows x 64 cols (1 KB).
    // lane i -> row_in_chunk = i>>3, LDS colgrp = i&7, global colgrp = (i&7)^(i>>3 &7)
    const int sr = lane >> 3;                 // 0..7 row in chunk
    const int gcol = ((lane & 7) ^ sr) << 3;  // swizzled global col (elems)
    const bf16* gA[4];
    const bf16* gB[4];
    bf16* lA[4];
    bf16* lB[4];
#pragma unroll
    for (int p = 0; p < 4; ++p) {
        int c = wave * 4 + p;                 // chunk 0..15
        gA[p] = A  + (size_t)(m0 + c * 8 + sr) * Kdim + gcol;
        gB[p] = Bt + (size_t)(n0 + c * 8 + sr) * Kdim + gcol;
        lA[p] = As + c * 512 + lane * 8;
        lB[p] = Bs + c * 512 + lane * 8;
    }

    const int wm = (wave >> 1) << 6;     // 0 / 64
    const int wn = (wave & 1) << 6;      // 0 / 64
    const int fr = lane & 15;            // m (A) / n (B) within 16-tile
    const int kg = lane >> 4;            // k-group 0..3
    const int f7 = fr & 7;

    f32x4 acc[4][4] = {};
    for (int k0 = 0; k0 < Kdim; k0 += 64) {
        __syncthreads();
#pragma unroll
        for (int p = 0; p < 4; ++p) {
            gload16(gA[p] + k0, lA[p]);
            gload16(gB[p] + k0, lB[p]);
        }
        __syncthreads();
#pragma unroll
        for (int ks = 0; ks < 2; ++ks) {
            bf16x8 af[4], bf_[4];
#pragma unroll
            for (int i = 0; i < 4; ++i) {
                int gq = (((ks << 2) | kg) ^ f7) << 3;
                af[i]  = *(const bf16x8*)&As[(wm + i * 16 + fr) * 64 + gq];
                bf_[i] = *(const bf16x8*)&Bs[(wn + i * 16 + fr) * 64 + gq];
            }
#pragma unroll
            for (int i = 0; i < 4; ++i)
#pragma unroll
                for (int j = 0; j < 4; ++j)
                    acc[i][j] = __builtin_amdgcn_mfma_f32_16x16x32_bf16(
                        af[i], bf_[j], acc[i][j], 0, 0, 0);
        }
    }

    // epilogue: C/D layout col(n)=lane&15, row(m)=kg*4+reg  [m89/m91 verified]
    const int baseRow = m0 + wm + kg * 4;
    const int baseCol = n0 + wn + fr;
#pragma unroll
    for (int i = 0; i < 4; ++i) {
#pragma unroll
        for (int r = 0; r < 4; ++r) {
            int m = baseRow + i * 16 + r;
            size_t rowoff = (size_t)m * Ndim + baseCol;
#pragma unroll
            for (int j = 0; j < 4; ++j) {
                float v = acc[i][j][r] + bias[baseCol + j * 16];
                if (EPI == 1) v = sigmoidf_(v);
                if (EPI == 2) v += add[rowoff + j * 16];
                if constexpr (sizeof(OutT) == 4)
                    ((float*)out)[rowoff + j * 16] = v;
                else
                    ((bf16*)out)[rowoff + j * 16] = f2bf(v);
            }
        }
    }
}

// ------------------------------------------------------------- SSM scan -----
// p[b,l,h,j,s] (bf16); j=0 delta(pre-sigmoid), j=1 B, j=2 C.
// h = sigmoid(delta)*h + B;  ssm = C*h.

// phase 1: per-chunk affine composition (4 waves = 4 h's per block)
__global__ __launch_bounds__(256) void scan_phase1(const bf16* __restrict__ p,
                                                   float* __restrict__ cA,
                                                   float* __restrict__ cB) {
    int c = blockIdx.x, b = blockIdx.z, s = threadIdx.x & 63;
    int h = blockIdx.y * 4 + (threadIdx.x >> 6);
    size_t base = ((size_t)(b * LL + c * CLN)) * N3 + h * (3 * DSS) + s;
    float a = 1.0f, bb = 0.0f;
    for (int i = 0; i < CLN; ++i) {
        float d = sigmoidf_(bf2f(p[base]));
        float Bv = bf2f(p[base + DSS]);
        a *= d;
        bb = d * bb + Bv;
        base += N3;
    }
    int idx = ((b * HH + h) * NCH + c) * DSS + s;
    cA[idx] = a;
    cB[idx] = bb;
}

// phase 2: serial prefix over chunks; h at chunk starts + h_last
__global__ __launch_bounds__(64) void scan_phase2(const float* __restrict__ state,
                                                  const float* __restrict__ cA,
                                                  const float* __restrict__ cB,
                                                  float* __restrict__ cH,
                                                  float* __restrict__ hlast) {
    int h = blockIdx.x, b = blockIdx.y, s = threadIdx.x;
    float hp = state[(b * HH + h) * DSS + s];
    int base = ((b * HH + h) * NCH) * DSS + s;
    for (int c = 0; c < NCH; ++c) {
        cH[base + c * DSS] = hp;
        hp = cA[base + c * DSS] * hp + cB[base + c * DSS];
    }
    hlast[(b * HH + h) * DSS + s] = hp;
}

// phase 3: replay within chunk; fused mixed = gate*C*h + (1-gate)*xn
__global__ __launch_bounds__(256) void scan_phase3(const bf16* __restrict__ p,
                                                   const float* __restrict__ cH,
                                                   const bf16* __restrict__ gate,
                                                   const bf16* __restrict__ xn,
                                                   bf16* __restrict__ mixed) {
    int c = blockIdx.x, b = blockIdx.z, s = threadIdx.x & 63;
    int h = blockIdx.y * 4 + (threadIdx.x >> 6);
    float hp = cH[((b * HH + h) * NCH + c) * DSS + s];
    size_t prow = ((size_t)(b * LL + c * CLN)) * N3 + h * (3 * DSS) + s;
    size_t grow = ((size_t)(b * LL + c * CLN)) * DD + h * DSS + s;
    for (int i = 0; i < CLN; ++i) {
        float d = sigmoidf_(bf2f(p[prow]));
        float Bv = bf2f(p[prow + DSS]);
        float Cv = bf2f(p[prow + 2 * DSS]);
        hp = d * hp + Bv;
        float ssm = Cv * hp;
        float g = bf2f(gate[grow]);
        float xv = bf2f(xn[grow]);
        mixed[grow] = f2bf(g * ssm + (1.0f - g) * xv);
        prow += N3;
        grow += DD;
    }
}

// ---------------------------------------------------------------------------
extern "C" void kernel_launch(void* const* d_in, const int* in_sizes, int n_in,
                              void* d_out, int out_size, void* d_ws, size_t ws_size,
                              hipStream_t stream) {
    const float* x      = (const float*)d_in[0];
    const float* state  = (const float*)d_in[1];
    const float* norm_w = (const float*)d_in[2];
    const float* conv_w = (const float*)d_in[3];
    const float* conv_b = (const float*)d_in[4];
    const float* pp_w   = (const float*)d_in[5];
    const float* pp_b   = (const float*)d_in[6];
    const float* gp_w   = (const float*)d_in[7];
    const float* gp_b   = (const float*)d_in[8];
    const float* op_w   = (const float*)d_in[9];
    const float* op_b   = (const float*)d_in[10];

    float* y     = (float*)d_out;                 // M*D floats
    float* hlast = y + (size_t)MM * DD;           // B*H*DS floats

    // ws: xn 32MB | xcbuf 32MB (xc -> pp_wT -> mixed) | p 96MB |
    //     cA,cB,cH 3MB | gp_wT 8MB | op_wT 8MB      total ~179MB
    const size_t BHND = (size_t)BB * HH * NCH * DSS;
    char* ws = (char*)d_ws;
    bf16* xn    = (bf16*)ws;
    bf16* xcbuf = xn + (size_t)MM * DD;
    bf16* p     = xcbuf + (size_t)MM * DD;
    float* cA   = (float*)(p + (size_t)MM * N3);
    float* cB   = cA + BHND;
    float* cH   = cB + BHND;
    bf16* gp_wT = (bf16*)(cH + BHND);
    bf16* op_wT = gp_wT + (size_t)DD * DD;
    bf16* pp_wT = xcbuf;   // 25MB fits in 32MB xc buffer (xc dead after gate GEMM)
    // gate (bf16) parked in d_out's y region; phase3 consumes it before the
    // final GEMM overwrites y.
    bf16* gate  = (bf16*)y;
    bf16* mixed = xcbuf;

    // 1. RMSNorm (fp32 -> bf16)
    rms_kernel<<<MM, 256, 0, stream>>>(x, norm_w, xn);
    // 2. causal conv + SiLU (bf16 -> bf16)
    conv_silu_kernel<<<dim3(LL, BB), 256, 0, stream>>>(xn, conv_w, conv_b, xcbuf);
    // 3a. gp_w -> bf16 transposed
    transpose_bf<<<dim3(DD / 32, DD / 32), 256, 0, stream>>>(gp_w, gp_wT, DD, DD);
    // 3b. gate = sigmoid(xc @ gp_w + gp_b)  (bf16 out)
    gemm_mfma<1, bf16><<<dim3(DD / 128, MM / 128), 256, 0, stream>>>(
        xcbuf, gp_wT, gp_b, nullptr, gate, DD, DD);
    // 4a. pp_w -> bf16 transposed (into xc buffer — xc is dead now)
    transpose_bf<<<dim3(N3 / 32, DD / 32), 256, 0, stream>>>(pp_w, pp_wT, DD, N3);
    // 4b. p = xn @ pp_w + pp_b  (bf16 out)
    gemm_mfma<0, bf16><<<dim3(N3 / 128, MM / 128), 256, 0, stream>>>(
        xn, pp_wT, pp_b, nullptr, p, N3, DD);
    // 5-7. chunked SSM scan fused with mixing (mixed overwrites pp_wT region)
    scan_phase1<<<dim3(NCH, HH / 4, BB), 256, 0, stream>>>(p, cA, cB);
    scan_phase2<<<dim3(HH, BB), 64, 0, stream>>>(state, cA, cB, cH, hlast);
    scan_phase3<<<dim3(NCH, HH / 4, BB), 256, 0, stream>>>(p, cH, gate, xn, mixed);
    // 8a. op_w -> bf16 transposed
    transpose_bf<<<dim3(DD / 32, DD / 32), 256, 0, stream>>>(op_w, op_wT, DD, DD);
    // 8b. y = mixed @ op_w + op_b + x
    gemm_mfma<2, float><<<dim3(DD / 128, MM / 128), 256, 0, stream>>>(
        mixed, op_wT, op_b, x, y, DD, DD);
}

// Round 5
// 682.541 us; speedup vs baseline: 6.4319x; 1.0274x over previous
//
#include <hip/hip_runtime.h>
#include <math.h>

// Problem constants (MambaBlock): B=2, L=4096, D=2048, H=32, DS=64, K=4
#define BB   2
#define LL   4096
#define DD   2048
#define HH   32
#define DSS  64
#define MM   (BB * LL)        // 8192 rows
#define N3   (3 * HH * DSS)   // 6144
#define NCH  64               // scan chunks
#define CLN  64               // steps per chunk (NCH*CLN == LL)
#define EPSF 1e-6f
#define GP_NB (DD / 128)      // 16 gate n-blocks
#define PP_NB (N3 / 128)      // 48 proj n-blocks

typedef unsigned short bf16;  // raw bf16 bits — we own the representation
typedef __attribute__((ext_vector_type(8))) short bf16x8;  // MFMA A/B frag (4 VGPRs)
typedef __attribute__((ext_vector_type(4))) float f32x4;   // MFMA C/D frag

__device__ __forceinline__ float bf2f(bf16 u) {
    union { unsigned int i; float f; } v;
    v.i = ((unsigned int)u) << 16;
    return v.f;
}
__device__ __forceinline__ bf16 f2bf(float f) {
    union { float f; unsigned int u; } v;
    v.f = f;
    unsigned int r = (v.u >> 16) & 1u;       // round to nearest even
    return (bf16)((v.u + 0x7fffu + r) >> 16);
}
__device__ __forceinline__ float sigmoidf_(float v) {
    return 1.0f / (1.0f + __expf(-v));
}
__device__ __forceinline__ void gload16(const void* g, void* l) {
    __builtin_amdgcn_global_load_lds(
        (const __attribute__((address_space(1))) void*)g,
        (__attribute__((address_space(3))) void*)l, 16, 0, 0);
}

// ---------------------------------------------------------------- RMSNorm ---
__global__ __launch_bounds__(256) void rms_kernel(const float* __restrict__ x,
                                                  const float* __restrict__ w,
                                                  bf16* __restrict__ xn) {
    int row = blockIdx.x;
    const float4* x4 = (const float4*)(x + (size_t)row * DD);
    ushort4* o4 = (ushort4*)(xn + (size_t)row * DD);
    const float4* w4 = (const float4*)w;
    int t = threadIdx.x;
    float4 v0 = x4[t], v1 = x4[t + 256];
    float ss = v0.x * v0.x + v0.y * v0.y + v0.z * v0.z + v0.w * v0.w +
               v1.x * v1.x + v1.y * v1.y + v1.z * v1.z + v1.w * v1.w;
#pragma unroll
    for (int off = 32; off >= 1; off >>= 1) ss += __shfl_down(ss, off, 64);
    __shared__ float red[4];
    if ((t & 63) == 0) red[t >> 6] = ss;
    __syncthreads();
    float tot = red[0] + red[1] + red[2] + red[3];
    float inv = 1.0f / sqrtf(tot * (1.0f / DD) + EPSF);
    float4 wa = w4[t], wb = w4[t + 256];
    ushort4 r0, r1;
    r0.x = f2bf(v0.x * inv * wa.x); r0.y = f2bf(v0.y * inv * wa.y);
    r0.z = f2bf(v0.z * inv * wa.z); r0.w = f2bf(v0.w * inv * wa.w);
    r1.x = f2bf(v1.x * inv * wb.x); r1.y = f2bf(v1.y * inv * wb.y);
    r1.z = f2bf(v1.z * inv * wb.z); r1.w = f2bf(v1.w * inv * wb.w);
    o4[t] = r0; o4[t + 256] = r1;
}

// ----------------------------------------------------- causal conv + SiLU ---
// Sliding-window: thread owns 4 d's (ushort4), walks CONV_LC l's; each xn
// element read exactly once. grid (LL/CONV_LC, D/1024, B).
#define CONV_LC 32
__global__ __launch_bounds__(256) void conv_silu_kernel(const bf16* __restrict__ xn,
                                                        const float* __restrict__ cw,
                                                        const float* __restrict__ cb,
                                                        bf16* __restrict__ xc) {
    int b = blockIdx.z;
    int l0 = blockIdx.x * CONV_LC;
    int d0 = blockIdx.y * 1024 + threadIdx.x * 4;
    float4 w[4];
    float bias[4];
#pragma unroll
    for (int j = 0; j < 4; ++j) {
        w[j] = ((const float4*)cw)[d0 + j];
        bias[j] = cb[d0 + j];
    }
    float win[3][4];
#pragma unroll
    for (int k = 0; k < 3; ++k) {
        int l = l0 - 3 + k;
        if (l >= 0) {
            ushort4 v = *(const ushort4*)&xn[((size_t)b * LL + l) * DD + d0];
            win[k][0] = bf2f(v.x); win[k][1] = bf2f(v.y);
            win[k][2] = bf2f(v.z); win[k][3] = bf2f(v.w);
        } else {
            win[k][0] = win[k][1] = win[k][2] = win[k][3] = 0.0f;
        }
    }
    size_t off = ((size_t)b * LL + l0) * DD + d0;
    for (int i = 0; i < CONV_LC; ++i) {
        ushort4 v = *(const ushort4*)&xn[off];
        float cur[4] = {bf2f(v.x), bf2f(v.y), bf2f(v.z), bf2f(v.w)};
        ushort4 o;
#pragma unroll
        for (int j = 0; j < 4; ++j) {
            float acc = bias[j] + win[0][j] * w[j].x + win[1][j] * w[j].y +
                        win[2][j] * w[j].z + cur[j] * w[j].w;
            float s = acc * sigmoidf_(acc);
            ((unsigned short*)&o)[j] = f2bf(s);
        }
        *(ushort4*)&xc[off] = o;
#pragma unroll
        for (int j = 0; j < 4; ++j) {
            win[0][j] = win[1][j]; win[1][j] = win[2][j]; win[2][j] = cur[j];
        }
        off += DD;
    }
}

// --------------------- all 3 weight transposes (fp32->bf16) in one dispatch --
// gp_w [DD][DD] -> gp_wT ; op_w [DD][DD] -> op_wT ; pp_w [DD][N3] -> pp_wT
__global__ __launch_bounds__(256) void transpose3(const float* __restrict__ gp_w,
                                                  const float* __restrict__ op_w,
                                                  const float* __restrict__ pp_w,
                                                  bf16* __restrict__ gp_wT,
                                                  bf16* __restrict__ op_wT,
                                                  bf16* __restrict__ pp_wT) {
    __shared__ float t[32][33];
    int bx = blockIdx.x;
    const float* W; bf16* WT; int Ndim;
    if (bx < 64)       { W = gp_w; WT = gp_wT; Ndim = DD; }
    else if (bx < 128) { W = op_w; WT = op_wT; Ndim = DD; bx -= 64; }
    else               { W = pp_w; WT = pp_wT; Ndim = N3; bx -= 128; }
    int n0 = bx << 5, k0 = blockIdx.y << 5;
    int tx = threadIdx.x & 31;
    int ty = threadIdx.x >> 5;   // 0..7
#pragma unroll
    for (int i = 0; i < 32; i += 8)
        t[ty + i][tx] = W[(size_t)(k0 + ty + i) * Ndim + n0 + tx];
    __syncthreads();
#pragma unroll
    for (int i = 0; i < 32; i += 8)
        WT[(size_t)(n0 + ty + i) * DD + k0 + tx] = f2bf(t[tx][ty + i]);
}

// ---------------------------- MFMA bf16 GEMM core (BK=64, XOR-swizzled LDS) --
// Computes one 128x128 tile of out = A @ Bt^T + bias with optional epilogue.
// EPI: 0 none, 1 sigmoid, 2 +add. K fixed = DD (2048).
template <int EPI, typename OutT>
__device__ __forceinline__ void gemm_tile(const bf16* __restrict__ A,
                                          const bf16* __restrict__ Bt,
                                          const float* __restrict__ bias,
                                          const float* __restrict__ add,
                                          OutT* __restrict__ out,
                                          int Ndim, int m0, int n0,
                                          bf16* As, bf16* Bs) {
    const int tid  = threadIdx.x;
    const int wave = tid >> 6;
    const int lane = tid & 63;
    const int sr = lane >> 3;                 // 0..7 row in chunk
    const int gcol = ((lane & 7) ^ sr) << 3;  // swizzled global col (elems)
    const bf16* gA[4];
    const bf16* gB[4];
    bf16* lA[4];
    bf16* lB[4];
#pragma unroll
    for (int p = 0; p < 4; ++p) {
        int c = wave * 4 + p;                 // chunk 0..15
        gA[p] = A  + (size_t)(m0 + c * 8 + sr) * DD + gcol;
        gB[p] = Bt + (size_t)(n0 + c * 8 + sr) * DD + gcol;
        lA[p] = As + c * 512 + lane * 8;
        lB[p] = Bs + c * 512 + lane * 8;
    }
    const int wm = (wave >> 1) << 6;     // 0 / 64
    const int wn = (wave & 1) << 6;      // 0 / 64
    const int fr = lane & 15;            // m (A) / n (B) within 16-tile
    const int kg = lane >> 4;            // k-group 0..3
    const int f7 = fr & 7;

    f32x4 acc[4][4] = {};
    for (int k0 = 0; k0 < DD; k0 += 64) {
        __syncthreads();
#pragma unroll
        for (int p = 0; p < 4; ++p) {
            gload16(gA[p] + k0, lA[p]);
            gload16(gB[p] + k0, lB[p]);
        }
        __syncthreads();
#pragma unroll
        for (int ks = 0; ks < 2; ++ks) {
            bf16x8 af[4], bf_[4];
#pragma unroll
            for (int i = 0; i < 4; ++i) {
                int gq = (((ks << 2) | kg) ^ f7) << 3;
                af[i]  = *(const bf16x8*)&As[(wm + i * 16 + fr) * 64 + gq];
                bf_[i] = *(const bf16x8*)&Bs[(wn + i * 16 + fr) * 64 + gq];
            }
#pragma unroll
            for (int i = 0; i < 4; ++i)
#pragma unroll
                for (int j = 0; j < 4; ++j)
                    acc[i][j] = __builtin_amdgcn_mfma_f32_16x16x32_bf16(
                        af[i], bf_[j], acc[i][j], 0, 0, 0);
        }
    }
    // epilogue: C/D layout col(n)=lane&15, row(m)=kg*4+reg  [m89/m91 verified]
    const int baseRow = m0 + wm + kg * 4;
    const int baseCol = n0 + wn + fr;
#pragma unroll
    for (int i = 0; i < 4; ++i) {
#pragma unroll
        for (int r = 0; r < 4; ++r) {
            int m = baseRow + i * 16 + r;
            size_t rowoff = (size_t)m * Ndim + baseCol;
#pragma unroll
            for (int j = 0; j < 4; ++j) {
                float v = acc[i][j][r] + bias[baseCol + j * 16];
                if (EPI == 1) v = sigmoidf_(v);
                if (EPI == 2) v += add[rowoff + j * 16];
                if constexpr (sizeof(OutT) == 4)
                    ((float*)out)[rowoff + j * 16] = v;
                else
                    ((bf16*)out)[rowoff + j * 16] = f2bf(v);
            }
        }
    }
}

// gate GEMM + proj GEMM merged into one dispatch. grid (GP_NB+PP_NB, MM/128).
__global__ __launch_bounds__(256) void gemm_gateproj(const bf16* __restrict__ xc,
                                                     const bf16* __restrict__ gp_wT,
                                                     const float* __restrict__ gp_b,
                                                     bf16* __restrict__ gate,
                                                     const bf16* __restrict__ xn,
                                                     const bf16* __restrict__ pp_wT,
                                                     const float* __restrict__ pp_b,
                                                     bf16* __restrict__ p) {
    __shared__ __align__(16) bf16 As[128 * 64];
    __shared__ __align__(16) bf16 Bs[128 * 64];
    const int m0 = blockIdx.y << 7;
    if (blockIdx.x < GP_NB) {
        gemm_tile<1, bf16>(xc, gp_wT, gp_b, nullptr, gate, DD,
                           m0, blockIdx.x << 7, As, Bs);
    } else {
        gemm_tile<0, bf16>(xn, pp_wT, pp_b, nullptr, p, N3,
                           m0, (blockIdx.x - GP_NB) << 7, As, Bs);
    }
}

// final out GEMM: y = mixed @ op_w + op_b + x
__global__ __launch_bounds__(256) void gemm_out(const bf16* __restrict__ mixed,
                                                const bf16* __restrict__ op_wT,
                                                const float* __restrict__ op_b,
                                                const float* __restrict__ x,
                                                float* __restrict__ y) {
    __shared__ __align__(16) bf16 As[128 * 64];
    __shared__ __align__(16) bf16 Bs[128 * 64];
    gemm_tile<2, float>(mixed, op_wT, op_b, x, y, DD,
                        blockIdx.y << 7, blockIdx.x << 7, As, Bs);
}

// ------------------------------------------------------------- SSM scan -----
// p[b,l,h,j,s] (bf16); j=0 delta(pre-sigmoid), j=1 B, j=2 C.
// h = sigmoid(delta)*h + B;  ssm = C*h.
__global__ __launch_bounds__(256) void scan_phase1(const bf16* __restrict__ p,
                                                   float* __restrict__ cA,
                                                   float* __restrict__ cB) {
    int c = blockIdx.x, b = blockIdx.z, s = threadIdx.x & 63;
    int h = blockIdx.y * 4 + (threadIdx.x >> 6);
    size_t base = ((size_t)(b * LL + c * CLN)) * N3 + h * (3 * DSS) + s;
    float a = 1.0f, bb = 0.0f;
    for (int i = 0; i < CLN; ++i) {
        float d = sigmoidf_(bf2f(p[base]));
        float Bv = bf2f(p[base + DSS]);
        a *= d;
        bb = d * bb + Bv;
        base += N3;
    }
    int idx = ((b * HH + h) * NCH + c) * DSS + s;
    cA[idx] = a;
    cB[idx] = bb;
}

__global__ __launch_bounds__(64) void scan_phase2(const float* __restrict__ state,
                                                  const float* __restrict__ cA,
                                                  const float* __restrict__ cB,
                                                  float* __restrict__ cH,
                                                  float* __restrict__ hlast) {
    int h = blockIdx.x, b = blockIdx.y, s = threadIdx.x;
    float hp = state[(b * HH + h) * DSS + s];
    int base = ((b * HH + h) * NCH) * DSS + s;
    for (int c = 0; c < NCH; ++c) {
        cH[base + c * DSS] = hp;
        hp = cA[base + c * DSS] * hp + cB[base + c * DSS];
    }
    hlast[(b * HH + h) * DSS + s] = hp;
}

__global__ __launch_bounds__(256) void scan_phase3(const bf16* __restrict__ p,
                                                   const float* __restrict__ cH,
                                                   const bf16* __restrict__ gate,
                                                   const bf16* __restrict__ xn,
                                                   bf16* __restrict__ mixed) {
    int c = blockIdx.x, b = blockIdx.z, s = threadIdx.x & 63;
    int h = blockIdx.y * 4 + (threadIdx.x >> 6);
    float hp = cH[((b * HH + h) * NCH + c) * DSS + s];
    size_t prow = ((size_t)(b * LL + c * CLN)) * N3 + h * (3 * DSS) + s;
    size_t grow = ((size_t)(b * LL + c * CLN)) * DD + h * DSS + s;
    for (int i = 0; i < CLN; ++i) {
        float d = sigmoidf_(bf2f(p[prow]));
        float Bv = bf2f(p[prow + DSS]);
        float Cv = bf2f(p[prow + 2 * DSS]);
        hp = d * hp + Bv;
        float ssm = Cv * hp;
        float g = bf2f(gate[grow]);
        float xv = bf2f(xn[grow]);
        mixed[grow] = f2bf(g * ssm + (1.0f - g) * xv);
        prow += N3;
        grow += DD;
    }
}

// ---------------------------------------------------------------------------
extern "C" void kernel_launch(void* const* d_in, const int* in_sizes, int n_in,
                              void* d_out, int out_size, void* d_ws, size_t ws_size,
                              hipStream_t stream) {
    const float* x      = (const float*)d_in[0];
    const float* state  = (const float*)d_in[1];
    const float* norm_w = (const float*)d_in[2];
    const float* conv_w = (const float*)d_in[3];
    const float* conv_b = (const float*)d_in[4];
    const float* pp_w   = (const float*)d_in[5];
    const float* pp_b   = (const float*)d_in[6];
    const float* gp_w   = (const float*)d_in[7];
    const float* gp_b   = (const float*)d_in[8];
    const float* op_w   = (const float*)d_in[9];
    const float* op_b   = (const float*)d_in[10];

    float* y     = (float*)d_out;                 // M*D floats (64 MB)
    float* hlast = y + (size_t)MM * DD;           // B*H*DS floats

    // ws: xn 32MB | xcbuf 32MB (xc -> mixed) | p 96MB | cA,cB,cH 3MB |
    //     gp_wT 8MB | op_wT 8MB                               total ~179MB
    // d_out y region (64MB): gate bf16 [0,32MB) | pp_wT bf16 [32,56MB)
    //   — both dead before gemm_out overwrites y with fp32 output.
    const size_t BHND = (size_t)BB * HH * NCH * DSS;
    char* ws = (char*)d_ws;
    bf16* xn    = (bf16*)ws;
    bf16* xcbuf = xn + (size_t)MM * DD;
    bf16* p     = xcbuf + (size_t)MM * DD;
    float* cA   = (float*)(p + (size_t)MM * N3);
    float* cB   = cA + BHND;
    float* cH   = cB + BHND;
    bf16* gp_wT = (bf16*)(cH + BHND);
    bf16* op_wT = gp_wT + (size_t)DD * DD;
    bf16* gate  = (bf16*)y;                       // 32MB
    bf16* pp_wT = gate + (size_t)MM * DD;         // 24MB, in upper half of y
    bf16* mixed = xcbuf;

    // 1. RMSNorm (fp32 -> bf16)
    rms_kernel<<<MM, 256, 0, stream>>>(x, norm_w, xn);
    // 2. causal conv + SiLU (sliding window)
    conv_silu_kernel<<<dim3(LL / CONV_LC, DD / 1024, BB), 256, 0, stream>>>(
        xn, conv_w, conv_b, xcbuf);
    // 3. all three weight transposes in one dispatch
    transpose3<<<dim3(320, DD / 32), 256, 0, stream>>>(gp_w, op_w, pp_w,
                                                       gp_wT, op_wT, pp_wT);
    // 4. gate = sigmoid(xc @ gp_w + gp_b)  AND  p = xn @ pp_w + pp_b (merged)
    gemm_gateproj<<<dim3(GP_NB + PP_NB, MM / 128), 256, 0, stream>>>(
        xcbuf, gp_wT, gp_b, gate, xn, pp_wT, pp_b, p);
    // 5-7. chunked SSM scan fused with mixing
    scan_phase1<<<dim3(NCH, HH / 4, BB), 256, 0, stream>>>(p, cA, cB);
    scan_phase2<<<dim3(HH, BB), 64, 0, stream>>>(state, cA, cB, cH, hlast);
    scan_phase3<<<dim3(NCH, HH / 4, BB), 256, 0, stream>>>(p, cH, gate, xn, mixed);
    // 8. y = mixed @ op_w + op_b + x
    gemm_out<<<dim3(GP_NB, MM / 128), 256, 0, stream>>>(mixed, op_wT, op_b, x, y);
}

// Round 6
// 666.450 us; speedup vs baseline: 6.5872x; 1.0241x over previous
//
#include <hip/hip_runtime.h>
#include <math.h>

// Problem constants (MambaBlock): B=2, L=4096, D=2048, H=32, DS=64, K=4
#define BB   2
#define LL   4096
#define DD   2048
#define HH   32
#define DSS  64
#define MM   (BB * LL)        // 8192 rows
#define N3   (3 * HH * DSS)   // 6144
#define NCH  64               // scan chunks
#define CLN  64               // steps per chunk (NCH*CLN == LL)
#define EPSF 1e-6f
#define GP_NB (DD / 128)      // 16 gate n-blocks
#define PP_NB (N3 / 128)      // 48 proj n-blocks
#define TR_NBX 320            // transpose blocks in n (64 gp + 64 op + 192 pp)
#define TR_NBY (DD / 32)      // 64 transpose blocks in k

typedef unsigned short bf16;  // raw bf16 bits — we own the representation
typedef __attribute__((ext_vector_type(8))) short bf16x8;  // MFMA A/B frag (4 VGPRs)
typedef __attribute__((ext_vector_type(4))) float f32x4;   // MFMA C/D frag

__device__ __forceinline__ float bf2f(bf16 u) {
    union { unsigned int i; float f; } v;
    v.i = ((unsigned int)u) << 16;
    return v.f;
}
__device__ __forceinline__ bf16 f2bf(float f) {
    union { float f; unsigned int u; } v;
    v.f = f;
    unsigned int r = (v.u >> 16) & 1u;       // round to nearest even
    return (bf16)((v.u + 0x7fffu + r) >> 16);
}
__device__ __forceinline__ float sigmoidf_(float v) {
    return 1.0f / (1.0f + __expf(-v));
}
__device__ __forceinline__ void gload16(const void* g, void* l) {
    __builtin_amdgcn_global_load_lds(
        (const __attribute__((address_space(1))) void*)g,
        (__attribute__((address_space(3))) void*)l, 16, 0, 0);
}

// -------------------- RMSNorm + all 3 weight transposes in ONE dispatch -----
// blocks [0, MM): rms row; blocks [MM, MM + TR_NBX*TR_NBY): transpose tiles.
__global__ __launch_bounds__(256) void rms_transpose(const float* __restrict__ x,
                                                     const float* __restrict__ w,
                                                     bf16* __restrict__ xn,
                                                     const float* __restrict__ gp_w,
                                                     const float* __restrict__ op_w,
                                                     const float* __restrict__ pp_w,
                                                     bf16* __restrict__ gp_wT,
                                                     bf16* __restrict__ op_wT,
                                                     bf16* __restrict__ pp_wT) {
    __shared__ float sh[32 * 33];
    int t = threadIdx.x;
    if (blockIdx.x < MM) {
        // ---- RMSNorm row ----
        int row = blockIdx.x;
        const float4* x4 = (const float4*)(x + (size_t)row * DD);
        ushort4* o4 = (ushort4*)(xn + (size_t)row * DD);
        const float4* w4 = (const float4*)w;
        float4 v0 = x4[t], v1 = x4[t + 256];
        float ss = v0.x * v0.x + v0.y * v0.y + v0.z * v0.z + v0.w * v0.w +
                   v1.x * v1.x + v1.y * v1.y + v1.z * v1.z + v1.w * v1.w;
#pragma unroll
        for (int off = 32; off >= 1; off >>= 1) ss += __shfl_down(ss, off, 64);
        if ((t & 63) == 0) sh[t >> 6] = ss;
        __syncthreads();
        float tot = sh[0] + sh[1] + sh[2] + sh[3];
        float inv = 1.0f / sqrtf(tot * (1.0f / DD) + EPSF);
        float4 wa = w4[t], wb = w4[t + 256];
        ushort4 r0, r1;
        r0.x = f2bf(v0.x * inv * wa.x); r0.y = f2bf(v0.y * inv * wa.y);
        r0.z = f2bf(v0.z * inv * wa.z); r0.w = f2bf(v0.w * inv * wa.w);
        r1.x = f2bf(v1.x * inv * wb.x); r1.y = f2bf(v1.y * inv * wb.y);
        r1.z = f2bf(v1.z * inv * wb.z); r1.w = f2bf(v1.w * inv * wb.w);
        o4[t] = r0; o4[t + 256] = r1;
    } else {
        // ---- weight transpose tile (32k x 32n), fp32 -> bf16 ----
        int id = blockIdx.x - MM;
        int bx = id % TR_NBX;
        int k0 = (id / TR_NBX) << 5;
        const float* W; bf16* WT; int Ndim;
        if (bx < 64)       { W = gp_w; WT = gp_wT; Ndim = DD; }
        else if (bx < 128) { W = op_w; WT = op_wT; Ndim = DD; bx -= 64; }
        else               { W = pp_w; WT = pp_wT; Ndim = N3; bx -= 128; }
        int n0 = bx << 5;
        float (*tl)[33] = (float (*)[33])sh;
        int tx = t & 31, ty = t >> 5;           // load: 8 k-rows x 32 n
#pragma unroll
        for (int i = 0; i < 32; i += 8)
            tl[ty + i][tx] = W[(size_t)(k0 + ty + i) * Ndim + n0 + tx];
        __syncthreads();
        int tx2 = t & 15, ty2 = t >> 4;         // store: ushort2 along k
#pragma unroll
        for (int i = 0; i < 32; i += 16) {
            int n = ty2 + i;
            ushort2 v = { f2bf(tl[tx2 * 2][n]), f2bf(tl[tx2 * 2 + 1][n]) };
            *(ushort2*)&WT[(size_t)(n0 + n) * DD + k0 + tx2 * 2] = v;
        }
    }
}

// ----------------------------------------------------- causal conv + SiLU ---
// Sliding-window: thread owns 4 d's (ushort4), walks CONV_LC l's.
#define CONV_LC 16
__global__ __launch_bounds__(256) void conv_silu_kernel(const bf16* __restrict__ xn,
                                                        const float* __restrict__ cw,
                                                        const float* __restrict__ cb,
                                                        bf16* __restrict__ xc) {
    int b = blockIdx.z;
    int l0 = blockIdx.x * CONV_LC;
    int d0 = blockIdx.y * 1024 + threadIdx.x * 4;
    float4 w[4];
    float bias[4];
#pragma unroll
    for (int j = 0; j < 4; ++j) {
        w[j] = ((const float4*)cw)[d0 + j];
        bias[j] = cb[d0 + j];
    }
    float win[3][4];
#pragma unroll
    for (int k = 0; k < 3; ++k) {
        int l = l0 - 3 + k;
        if (l >= 0) {
            ushort4 v = *(const ushort4*)&xn[((size_t)b * LL + l) * DD + d0];
            win[k][0] = bf2f(v.x); win[k][1] = bf2f(v.y);
            win[k][2] = bf2f(v.z); win[k][3] = bf2f(v.w);
        } else {
            win[k][0] = win[k][1] = win[k][2] = win[k][3] = 0.0f;
        }
    }
    size_t off = ((size_t)b * LL + l0) * DD + d0;
#pragma unroll 4
    for (int i = 0; i < CONV_LC; ++i) {
        ushort4 v = *(const ushort4*)&xn[off];
        float cur[4] = {bf2f(v.x), bf2f(v.y), bf2f(v.z), bf2f(v.w)};
        ushort4 o;
#pragma unroll
        for (int j = 0; j < 4; ++j) {
            float acc = bias[j] + win[0][j] * w[j].x + win[1][j] * w[j].y +
                        win[2][j] * w[j].z + cur[j] * w[j].w;
            float s = acc * sigmoidf_(acc);
            ((unsigned short*)&o)[j] = f2bf(s);
        }
        *(ushort4*)&xc[off] = o;
#pragma unroll
        for (int j = 0; j < 4; ++j) {
            win[0][j] = win[1][j]; win[1][j] = win[2][j]; win[2][j] = cur[j];
        }
        off += DD;
    }
}

// ---------------------------- MFMA bf16 GEMM core (BK=64, XOR-swizzled LDS) --
// Computes one 128x128 tile of out = A @ Bt^T + bias with optional epilogue.
// EPI: 0 none, 1 sigmoid, 2 +add. K fixed = DD (2048).
template <int EPI, typename OutT>
__device__ __forceinline__ void gemm_tile(const bf16* __restrict__ A,
                                          const bf16* __restrict__ Bt,
                                          const float* __restrict__ bias,
                                          const float* __restrict__ add,
                                          OutT* __restrict__ out,
                                          int Ndim, int m0, int n0,
                                          bf16* As, bf16* Bs) {
    const int tid  = threadIdx.x;
    const int wave = tid >> 6;
    const int lane = tid & 63;
    const int sr = lane >> 3;                 // 0..7 row in chunk
    const int gcol = ((lane & 7) ^ sr) << 3;  // swizzled global col (elems)
    const bf16* gA[4];
    const bf16* gB[4];
    bf16* lA[4];
    bf16* lB[4];
#pragma unroll
    for (int p = 0; p < 4; ++p) {
        int c = wave * 4 + p;                 // chunk 0..15
        gA[p] = A  + (size_t)(m0 + c * 8 + sr) * DD + gcol;
        gB[p] = Bt + (size_t)(n0 + c * 8 + sr) * DD + gcol;
        lA[p] = As + c * 512 + lane * 8;
        lB[p] = Bs + c * 512 + lane * 8;
    }
    const int wm = (wave >> 1) << 6;     // 0 / 64
    const int wn = (wave & 1) << 6;      // 0 / 64
    const int fr = lane & 15;            // m (A) / n (B) within 16-tile
    const int kg = lane >> 4;            // k-group 0..3
    const int f7 = fr & 7;

    f32x4 acc[4][4] = {};
    for (int k0 = 0; k0 < DD; k0 += 64) {
        __syncthreads();
#pragma unroll
        for (int p = 0; p < 4; ++p) {
            gload16(gA[p] + k0, lA[p]);
            gload16(gB[p] + k0, lB[p]);
        }
        __syncthreads();
#pragma unroll
        for (int ks = 0; ks < 2; ++ks) {
            bf16x8 af[4], bf_[4];
#pragma unroll
            for (int i = 0; i < 4; ++i) {
                int gq = (((ks << 2) | kg) ^ f7) << 3;
                af[i]  = *(const bf16x8*)&As[(wm + i * 16 + fr) * 64 + gq];
                bf_[i] = *(const bf16x8*)&Bs[(wn + i * 16 + fr) * 64 + gq];
            }
#pragma unroll
            for (int i = 0; i < 4; ++i)
#pragma unroll
                for (int j = 0; j < 4; ++j)
                    acc[i][j] = __builtin_amdgcn_mfma_f32_16x16x32_bf16(
                        af[i], bf_[j], acc[i][j], 0, 0, 0);
        }
    }
    // epilogue: C/D layout col(n)=lane&15, row(m)=kg*4+reg  [m89/m91 verified]
    const int baseRow = m0 + wm + kg * 4;
    const int baseCol = n0 + wn + fr;
#pragma unroll
    for (int i = 0; i < 4; ++i) {
#pragma unroll
        for (int r = 0; r < 4; ++r) {
            int m = baseRow + i * 16 + r;
            size_t rowoff = (size_t)m * Ndim + baseCol;
#pragma unroll
            for (int j = 0; j < 4; ++j) {
                float v = acc[i][j][r] + bias[baseCol + j * 16];
                if (EPI == 1) v = sigmoidf_(v);
                if (EPI == 2) v += add[rowoff + j * 16];
                if constexpr (sizeof(OutT) == 4)
                    ((float*)out)[rowoff + j * 16] = v;
                else
                    ((bf16*)out)[rowoff + j * 16] = f2bf(v);
            }
        }
    }
}

// gate GEMM + proj GEMM merged into one dispatch. grid (GP_NB+PP_NB, MM/128).
__global__ __launch_bounds__(256) void gemm_gateproj(const bf16* __restrict__ xc,
                                                     const bf16* __restrict__ gp_wT,
                                                     const float* __restrict__ gp_b,
                                                     bf16* __restrict__ gate,
                                                     const bf16* __restrict__ xn,
                                                     const bf16* __restrict__ pp_wT,
                                                     const float* __restrict__ pp_b,
                                                     bf16* __restrict__ p) {
    __shared__ __align__(16) bf16 As[128 * 64];
    __shared__ __align__(16) bf16 Bs[128 * 64];
    const int m0 = blockIdx.y << 7;
    if (blockIdx.x < GP_NB) {
        gemm_tile<1, bf16>(xc, gp_wT, gp_b, nullptr, gate, DD,
                           m0, blockIdx.x << 7, As, Bs);
    } else {
        gemm_tile<0, bf16>(xn, pp_wT, pp_b, nullptr, p, N3,
                           m0, (blockIdx.x - GP_NB) << 7, As, Bs);
    }
}

// final out GEMM: y = mixed @ op_w + op_b + x
__global__ __launch_bounds__(256) void gemm_out(const bf16* __restrict__ mixed,
                                                const bf16* __restrict__ op_wT,
                                                const float* __restrict__ op_b,
                                                const float* __restrict__ x,
                                                float* __restrict__ y) {
    __shared__ __align__(16) bf16 As[128 * 64];
    __shared__ __align__(16) bf16 Bs[128 * 64];
    gemm_tile<2, float>(mixed, op_wT, op_b, x, y, DD,
                        blockIdx.y << 7, blockIdx.x << 7, As, Bs);
}

// ------------------------------------------------------------- SSM scan -----
// p[b,l,h,j,s] (bf16); j=0 delta(pre-sigmoid), j=1 B, j=2 C.
// h = sigmoid(delta)*h + B;  ssm = C*h.

// phase 1: per-chunk affine composition (4 h's per 256-thread block)
__global__ __launch_bounds__(256) void scan_phase1(const bf16* __restrict__ p,
                                                   float* __restrict__ cA,
                                                   float* __restrict__ cB) {
    int c = blockIdx.x, b = blockIdx.z, s = threadIdx.x & 63;
    int h = blockIdx.y * 4 + (threadIdx.x >> 6);
    size_t base = ((size_t)(b * LL + c * CLN)) * N3 + h * (3 * DSS) + s;
    float a = 1.0f, bb = 0.0f;
#pragma unroll 8
    for (int i = 0; i < CLN; ++i) {
        float d = sigmoidf_(bf2f(p[base]));
        float Bv = bf2f(p[base + DSS]);
        a *= d;
        bb = d * bb + Bv;
        base += N3;
    }
    int idx = ((b * HH + h) * NCH + c) * DSS + s;
    cA[idx] = a;
    cB[idx] = bb;
}

// phase 3: per-block chunk-prefix from cA/cB, then replay fused with
// mixed = gate*C*h + (1-gate)*xn; block c==NCH-1 also emits h_last.
__global__ __launch_bounds__(256) void scan_phase3(const bf16* __restrict__ p,
                                                   const float* __restrict__ cA,
                                                   const float* __restrict__ cB,
                                                   const float* __restrict__ state,
                                                   const bf16* __restrict__ gate,
                                                   const bf16* __restrict__ xn,
                                                   bf16* __restrict__ mixed,
                                                   float* __restrict__ hlast) {
    int c = blockIdx.x, b = blockIdx.z, s = threadIdx.x & 63;
    int h = blockIdx.y * 4 + (threadIdx.x >> 6);
    // chunk prefix: compose chunks 0..c-1 onto the initial state
    float hp = state[(b * HH + h) * DSS + s];
    int cbase = ((b * HH + h) * NCH) * DSS + s;
    for (int cc = 0; cc < c; ++cc)
        hp = cA[cbase + cc * DSS] * hp + cB[cbase + cc * DSS];
    // replay + mix
    size_t prow = ((size_t)(b * LL + c * CLN)) * N3 + h * (3 * DSS) + s;
    size_t grow = ((size_t)(b * LL + c * CLN)) * DD + h * DSS + s;
#pragma unroll 4
    for (int i = 0; i < CLN; ++i) {
        float d = sigmoidf_(bf2f(p[prow]));
        float Bv = bf2f(p[prow + DSS]);
        float Cv = bf2f(p[prow + 2 * DSS]);
        hp = d * hp + Bv;
        float ssm = Cv * hp;
        float g = bf2f(gate[grow]);
        float xv = bf2f(xn[grow]);
        mixed[grow] = f2bf(g * ssm + (1.0f - g) * xv);
        prow += N3;
        grow += DD;
    }
    if (c == NCH - 1) hlast[(b * HH + h) * DSS + s] = hp;
}

// ---------------------------------------------------------------------------
extern "C" void kernel_launch(void* const* d_in, const int* in_sizes, int n_in,
                              void* d_out, int out_size, void* d_ws, size_t ws_size,
                              hipStream_t stream) {
    const float* x      = (const float*)d_in[0];
    const float* state  = (const float*)d_in[1];
    const float* norm_w = (const float*)d_in[2];
    const float* conv_w = (const float*)d_in[3];
    const float* conv_b = (const float*)d_in[4];
    const float* pp_w   = (const float*)d_in[5];
    const float* pp_b   = (const float*)d_in[6];
    const float* gp_w   = (const float*)d_in[7];
    const float* gp_b   = (const float*)d_in[8];
    const float* op_w   = (const float*)d_in[9];
    const float* op_b   = (const float*)d_in[10];

    float* y     = (float*)d_out;                 // M*D floats (64 MB)
    float* hlast = y + (size_t)MM * DD;           // B*H*DS floats

    // ws: xn 32MB | xcbuf 32MB (xc -> mixed) | p 96MB | cA,cB 2MB |
    //     gp_wT 8MB | op_wT 8MB                               total ~178MB
    // d_out y region (64MB): gate bf16 [0,32MB) | pp_wT bf16 [32,56MB)
    //   — both dead before gemm_out overwrites y with fp32 output.
    const size_t BHND = (size_t)BB * HH * NCH * DSS;
    char* ws = (char*)d_ws;
    bf16* xn    = (bf16*)ws;
    bf16* xcbuf = xn + (size_t)MM * DD;
    bf16* p     = xcbuf + (size_t)MM * DD;
    float* cA   = (float*)(p + (size_t)MM * N3);
    float* cB   = cA + BHND;
    bf16* gp_wT = (bf16*)(cB + BHND);
    bf16* op_wT = gp_wT + (size_t)DD * DD;
    bf16* gate  = (bf16*)y;                       // 32MB
    bf16* pp_wT = gate + (size_t)MM * DD;         // 24MB, in upper half of y
    bf16* mixed = xcbuf;

    // 1. RMSNorm + all three weight transposes (one dispatch)
    rms_transpose<<<MM + TR_NBX * TR_NBY, 256, 0, stream>>>(
        x, norm_w, xn, gp_w, op_w, pp_w, gp_wT, op_wT, pp_wT);
    // 2. causal conv + SiLU (sliding window)
    conv_silu_kernel<<<dim3(LL / CONV_LC, DD / 1024, BB), 256, 0, stream>>>(
        xn, conv_w, conv_b, xcbuf);
    // 3. gate = sigmoid(xc @ gp_w + gp_b)  AND  p = xn @ pp_w + pp_b (merged)
    gemm_gateproj<<<dim3(GP_NB + PP_NB, MM / 128), 256, 0, stream>>>(
        xcbuf, gp_wT, gp_b, gate, xn, pp_wT, pp_b, p);
    // 4. per-chunk scan summaries
    scan_phase1<<<dim3(NCH, HH / 4, BB), 256, 0, stream>>>(p, cA, cB);
    // 5. prefix + replay + mix + h_last (phase2 folded in)
    scan_phase3<<<dim3(NCH, HH / 4, BB), 256, 0, stream>>>(
        p, cA, cB, state, gate, xn, mixed, hlast);
    // 6. y = mixed @ op_w + op_b + x
    gemm_out<<<dim3(GP_NB, MM / 128), 256, 0, stream>>>(mixed, op_wT, op_b, x, y);
}